// Round 1
// baseline (733.400 us; speedup 1.0000x reference)
//
#include <hip/hip_runtime.h>
#include <hip/hip_bf16.h>

// Problem constants
#define B_    32
#define N_    32
#define E_    128
#define CIN_  64
#define COUT_ 128
#define H_    128
#define W_    128

using bf16x8 = __attribute__((ext_vector_type(8))) short;
using sh4    = __attribute__((ext_vector_type(4))) short;
using f32x4  = __attribute__((ext_vector_type(4))) float;

static __device__ __forceinline__ unsigned short f2bf(float f) {
  union { float f; unsigned u; } v; v.f = f;
  unsigned r = v.u + 0x7FFFu + ((v.u >> 16) & 1u);   // RNE
  return (unsigned short)(r >> 16);
}

// ---------------------------------------------------------------------------
// Pack conv_w [COUT][CIN][3][3] fp32 -> Wp [tap][COUT][CIN] bf16
// ---------------------------------------------------------------------------
__global__ void pack_w_kernel(const float* __restrict__ conv_w, short* __restrict__ Wp) {
  int idx = blockIdx.x * 256 + threadIdx.x;
  if (idx >= COUT_ * CIN_ * 9) return;
  int cout = idx / (CIN_ * 9);
  int rem  = idx % (CIN_ * 9);
  int ci   = rem / 9;
  int tap  = rem % 9;
  Wp[(tap * COUT_ + cout) * CIN_ + ci] = (short)f2bf(conv_w[idx]);
}

// ---------------------------------------------------------------------------
// QKV: qkv[mat][b][n][k] = sum_f x[b][n][f] * W[f][k],  x = [node || goal]
// grid (8 kgroups, 3 mats, 32 b), block 256
// ---------------------------------------------------------------------------
__global__ void qkv_kernel(const float* __restrict__ node_embeds,
                           const float* __restrict__ goal_embed,
                           const float* __restrict__ wQ,
                           const float* __restrict__ wK,
                           const float* __restrict__ wV,
                           float* __restrict__ qkv) {
  __shared__ float x[32][260];   // 256 + pad4 -> 1040B rows, 16B aligned
  int tid = threadIdx.x;
  int kg = blockIdx.x, mat = blockIdx.y, b = blockIdx.z;
  const float* W = (mat == 0) ? wQ : (mat == 1) ? wK : wV;
  for (int e = tid; e < 4096; e += 256) x[e >> 7][e & 127] = node_embeds[e];
  for (int e = tid; e < 4096; e += 256) x[e >> 7][128 + (e & 127)] = goal_embed[b * 128 + (e & 127)];
  __syncthreads();
  int k  = kg * 16 + (tid & 15);
  int n0 = tid >> 4, n1 = n0 + 16;
  float a0 = 0.f, a1 = 0.f;
  for (int f = 0; f < 256; f += 4) {
    float4 xv0 = *(const float4*)&x[n0][f];
    float4 xv1 = *(const float4*)&x[n1][f];
    float w0 = W[(f + 0) * 128 + k];
    float w1 = W[(f + 1) * 128 + k];
    float w2 = W[(f + 2) * 128 + k];
    float w3 = W[(f + 3) * 128 + k];
    a0 += xv0.x * w0 + xv0.y * w1 + xv0.z * w2 + xv0.w * w3;
    a1 += xv1.x * w0 + xv1.y * w1 + xv1.z * w2 + xv1.w * w3;
  }
  int base = (mat * 32 + b) * 32;
  qkv[(base + n0) * 128 + k] = a0;
  qkv[(base + n1) * 128 + k] = a1;
}

// ---------------------------------------------------------------------------
// scores + softmax + P@V -> atten[b][q][k].  grid 32 (b), block 256
// ---------------------------------------------------------------------------
__global__ void attn_kernel(const float* __restrict__ qkv, float* __restrict__ atten) {
  __shared__ float QS[32][132], KS[32][132], VS[32][132];
  __shared__ float S[32][33];
  int tid = threadIdx.x, b = blockIdx.x;
  const float* q0 = qkv + b * 4096;
  const float* k0 = qkv + 131072 + b * 4096;
  const float* v0 = qkv + 262144 + b * 4096;
  for (int e = tid; e < 4096; e += 256) {
    int n = e >> 7, k = e & 127;
    QS[n][k] = q0[e]; KS[n][k] = k0[e]; VS[n][k] = v0[e];
  }
  __syncthreads();
  for (int p = tid; p < 1024; p += 256) {
    int qi = p >> 5, ni = p & 31;
    float acc = 0.f;
    for (int k = 0; k < 128; k += 4) {
      float4 a = *(const float4*)&QS[qi][k];
      float4 c = *(const float4*)&KS[ni][k];
      acc += a.x * c.x + a.y * c.y + a.z * c.z + a.w * c.w;
    }
    S[qi][ni] = acc * 0.08838834764831845f;  // 1/sqrt(128)
  }
  __syncthreads();
  if (tid < 32) {
    float mx = -1e30f;
    for (int n = 0; n < 32; ++n) mx = fmaxf(mx, S[tid][n]);
    float sum = 0.f;
    for (int n = 0; n < 32; ++n) { float e = __expf(S[tid][n] - mx); S[tid][n] = e; sum += e; }
    float inv = 1.f / sum;
    for (int n = 0; n < 32; ++n) S[tid][n] *= inv;
  }
  __syncthreads();
  int qi = tid >> 3, ks = (tid & 7) * 16;
  float4 A0 = {0,0,0,0}, A1 = {0,0,0,0}, A2 = {0,0,0,0}, A3 = {0,0,0,0};
  for (int n = 0; n < 32; ++n) {
    float p = S[qi][n];
    float4 v_0 = *(const float4*)&VS[n][ks];
    float4 v_1 = *(const float4*)&VS[n][ks + 4];
    float4 v_2 = *(const float4*)&VS[n][ks + 8];
    float4 v_3 = *(const float4*)&VS[n][ks + 12];
    A0.x += p * v_0.x; A0.y += p * v_0.y; A0.z += p * v_0.z; A0.w += p * v_0.w;
    A1.x += p * v_1.x; A1.y += p * v_1.y; A1.z += p * v_1.z; A1.w += p * v_1.w;
    A2.x += p * v_2.x; A2.y += p * v_2.y; A2.z += p * v_2.z; A2.w += p * v_2.w;
    A3.x += p * v_3.x; A3.y += p * v_3.y; A3.z += p * v_3.z; A3.w += p * v_3.w;
  }
  float* op = atten + (b * 32 + qi) * 128 + ks;
  *(float4*)&op[0] = A0; *(float4*)&op[4] = A1; *(float4*)&op[8] = A2; *(float4*)&op[12] = A3;
}

// ---------------------------------------------------------------------------
// out_node[b][n][o] = fb[o] + sum_k atten[b][n][k] * fw[o][k]
// grid (32 n, 32 b), block 128
// ---------------------------------------------------------------------------
__global__ void final_kernel(const float* __restrict__ atten, const float* __restrict__ fw,
                             const float* __restrict__ fb, float* __restrict__ out_node) {
  __shared__ float ar[128];
  int tid = threadIdx.x;
  int n = blockIdx.x, b = blockIdx.y;
  ar[tid] = atten[(b * 32 + n) * 128 + tid];
  __syncthreads();
  const float* fr = fw + tid * 128;
  float acc = fb[tid];
  for (int k = 0; k < 128; k += 4) {
    float4 f = *(const float4*)&fr[k];
    acc += ar[k] * f.x + ar[k + 1] * f.y + ar[k + 2] * f.z + ar[k + 3] * f.w;
  }
  out_node[(b * 32 + n) * 128 + tid] = acc;
}

// ---------------------------------------------------------------------------
// Fused conv3x3 (bf16 implicit GEMM, MFMA 16x16x32) + gather-add epilogue
// grid (64 ytiles, 2 xtiles, 32 b), block 256 (4 waves)
// C tile = 128 cout x 128 spatial (2 rows x 64 cols); K = 9 taps x 64 ci
// ---------------------------------------------------------------------------
#define CIP 68   // padded ci (bf16 elems): 136B stride -> b64 frag reads conflict-free
#define TLX 66   // 64 + 2 halo columns
__global__ __launch_bounds__(256) void conv_kernel(
    const float* __restrict__ state, const float* __restrict__ conv_b,
    const int* __restrict__ game_board, const int* __restrict__ char_to_node,
    const short* __restrict__ Wp, const float* __restrict__ out_node,
    float* __restrict__ out) {
  __shared__ short tile[4 * TLX * CIP];   // 35904 B, layout [y][x][ci]
  int tid = threadIdx.x;
  int lane = tid & 63, wave = tid >> 6;
  int y0 = blockIdx.x * 2;
  int x0 = blockIdx.y * 64;
  int b  = blockIdx.z;

  // ---- stage input tile (rows y0-1..y0+2, cols x0-1..x0+64), fp32->bf16 ----
  for (int task = wave; task < 128; task += 4) {
    int cp = task >> 2;       // ci pair: ci = 2cp, 2cp+1
    int yy = task & 3;
    int gy = y0 - 1 + yy;
    const float* srow = state + ((b * 64 + 2 * cp) * 128 + gy) * 128;
    {
      int xt = lane, gx = x0 - 1 + xt;
      float v0 = 0.f, v1 = 0.f;
      if (gy >= 0 && gy < 128 && gx >= 0 && gx < 128) { v0 = srow[gx]; v1 = srow[16384 + gx]; }
      unsigned pk = (unsigned)f2bf(v0) | ((unsigned)f2bf(v1) << 16);
      *(unsigned*)&tile[(yy * TLX + xt) * CIP + 2 * cp] = pk;
    }
    if (lane < 2) {
      int xt = 64 + lane, gx = x0 - 1 + xt;
      float v0 = 0.f, v1 = 0.f;
      if (gy >= 0 && gy < 128 && gx >= 0 && gx < 128) { v0 = srow[gx]; v1 = srow[16384 + gx]; }
      unsigned pk = (unsigned)f2bf(v0) | ((unsigned)f2bf(v1) << 16);
      *(unsigned*)&tile[(yy * TLX + xt) * CIP + 2 * cp] = pk;
    }
  }
  __syncthreads();

  int q = lane >> 4, i = lane & 15;
  int mtset = (wave >> 1) * 4;   // m-tile base: waves {0,1}->0, {2,3}->4
  int ty    = wave & 1;          // spatial row within tile

  f32x4 acc[4][4];
#pragma unroll
  for (int m = 0; m < 4; ++m)
#pragma unroll
    for (int n = 0; n < 4; ++n) acc[m][n] = (f32x4){0.f, 0.f, 0.f, 0.f};

  // A-frag: Wp[t][m][h*32 + q*8 + j], m = (mtset+mtl)*16 + i
  const short* wbase = Wp + i * 64 + q * 8;
  bf16x8 aF[4];
#pragma unroll
  for (int m = 0; m < 4; ++m) aF[m] = *(const bf16x8*)(wbase + (mtset + m) * 1024);

  int base_cell = (ty * TLX + i) * CIP + q * 8;

  for (int chunk = 0; chunk < 18; ++chunk) {
    int t = chunk >> 1, h = chunk & 1;
    int kh = t / 3, kw = t - kh * 3;
    int off = (kh * TLX + kw) * CIP + h * 32;
    bf16x8 bF[4];
#pragma unroll
    for (int ntl = 0; ntl < 4; ++ntl) {
      const short* p = tile + base_cell + ntl * (16 * CIP) + off;
      sh4 lo = *(const sh4*)(p);
      sh4 hi = *(const sh4*)(p + 4);
      bF[ntl] = __builtin_shufflevector(lo, hi, 0, 1, 2, 3, 4, 5, 6, 7);
    }
    bf16x8 aN[4];
    if (chunk < 17) {                       // prefetch next chunk's A-frags (L2-hit)
      int c2 = chunk + 1;
      const short* wb2 = wbase + (c2 >> 1) * 8192 + (c2 & 1) * 32;
#pragma unroll
      for (int m = 0; m < 4; ++m) aN[m] = *(const bf16x8*)(wb2 + (mtset + m) * 1024);
    }
#pragma unroll
    for (int m = 0; m < 4; ++m)
#pragma unroll
      for (int n = 0; n < 4; ++n)
        acc[m][n] = __builtin_amdgcn_mfma_f32_16x16x32_bf16(aF[m], bF[n], acc[m][n], 0, 0, 0);
    if (chunk < 17) {
#pragma unroll
      for (int m = 0; m < 4; ++m) aF[m] = aN[m];
    }
  }

  // ---- epilogue: bias + gather(out_node) + store ----
  int gy = y0 + ty;
#pragma unroll
  for (int ntl = 0; ntl < 4; ++ntl) {
    int gx = x0 + ntl * 16 + i;
    int gb = game_board[(b * 128 + gy) * 128 + gx];
    bool valid = (gb >= 0 && gb < 32);
    int nidx = 0;
    if (valid) { nidx = char_to_node[gb]; nidx = nidx < 0 ? 0 : (nidx > 31 ? 31 : nidx); }
    const float* gn = out_node + (b * 32 + nidx) * 128;
#pragma unroll
    for (int m = 0; m < 4; ++m) {
      int c0 = (mtset + m) * 16 + q * 4;          // cout of reg 0
      float4 bias = *(const float4*)(conv_b + c0);
      float4 g = valid ? *(const float4*)(gn + c0) : make_float4(0.f, 0.f, 0.f, 0.f);
      f32x4 a = acc[m][ntl];
      int obase = (b * 128 + c0) * 16384 + gy * 128 + gx;
      out[obase]         = a[0] + bias.x + g.x;
      out[obase + 16384] = a[1] + bias.y + g.y;
      out[obase + 32768] = a[2] + bias.z + g.z;
      out[obase + 49152] = a[3] + bias.w + g.w;
    }
  }
}

// ---------------------------------------------------------------------------
extern "C" void kernel_launch(void* const* d_in, const int* in_sizes, int n_in,
                              void* d_out, int out_size, void* d_ws, size_t ws_size,
                              hipStream_t stream) {
  const int*   game_board   = (const int*)  d_in[0];
  const float* state        = (const float*)d_in[1];
  const float* node_embeds  = (const float*)d_in[2];
  const float* goal_embed   = (const float*)d_in[3];
  const int*   char_to_node = (const int*)  d_in[4];
  const float* conv_w       = (const float*)d_in[5];
  const float* conv_b       = (const float*)d_in[6];
  const float* wQ           = (const float*)d_in[7];
  const float* wK           = (const float*)d_in[8];
  const float* wV           = (const float*)d_in[9];
  const float* final_w      = (const float*)d_in[10];
  const float* final_b      = (const float*)d_in[11];
  float* out = (float*)d_out;

  char* ws = (char*)d_ws;
  short* Wp       = (short*)(ws);             // 147456 B  bf16 weights [9][128][64]
  float* qkv      = (float*)(ws + 147456);    // 1572864 B [3][32][32][128] fp32
  float* atten    = (float*)(ws + 1720320);   // 524288 B  [32][32][128] fp32
  float* out_node = (float*)(ws + 2244608);   // 524288 B  [32][32][128] fp32

  hipLaunchKernelGGL(pack_w_kernel, dim3(288), dim3(256), 0, stream, conv_w, Wp);
  hipLaunchKernelGGL(qkv_kernel, dim3(8, 3, 32), dim3(256), 0, stream,
                     node_embeds, goal_embed, wQ, wK, wV, qkv);
  hipLaunchKernelGGL(attn_kernel, dim3(32), dim3(256), 0, stream, qkv, atten);
  hipLaunchKernelGGL(final_kernel, dim3(32, 32), dim3(128), 0, stream, atten, final_w, final_b, out_node);
  hipLaunchKernelGGL(conv_kernel, dim3(64, 2, 32), dim3(256), 0, stream,
                     state, conv_b, game_board, char_to_node, Wp, out_node, out);
}

// Round 2
// 618.247 us; speedup vs baseline: 1.1863x; 1.1863x over previous
//
#include <hip/hip_runtime.h>
#include <hip/hip_bf16.h>

// Problem constants
#define B_    32
#define N_    32
#define E_    128
#define CIN_  64
#define COUT_ 128
#define H_    128
#define W_    128

using bf16x8 = __attribute__((ext_vector_type(8))) short;
using f32x4  = __attribute__((ext_vector_type(4))) float;

static __device__ __forceinline__ unsigned short f2bf(float f) {
  union { float f; unsigned u; } v; v.f = f;
  unsigned r = v.u + 0x7FFFu + ((v.u >> 16) & 1u);   // RNE
  return (unsigned short)(r >> 16);
}

// async global->LDS, 16B per lane (global_load_lds_dwordx4)
static __device__ __forceinline__ void gl2lds16(const void* g, void* l) {
  __builtin_amdgcn_global_load_lds(
      (const __attribute__((address_space(1))) unsigned int*)g,
      (__attribute__((address_space(3))) unsigned int*)l, 16, 0, 0);
}

// ---------------------------------------------------------------------------
// prep_kernel: one launch doing 4 independent jobs, selected by blockIdx.x
//   [0,4096)    : NCHW fp32 -> padded NHWC bf16 transpose (one (b,y) row each)
//                 nhwc[b][y+1][x+1][ci], 16B-chunk rotation ((k16 + xp) & 7)
//                 + zero this row's x-pad cells (cell 0, cells 129..135)
//   [4096,4160) : zero the y-pad rows (yp = 0 and 129 for each b)
//   [4160,4448) : pack conv_w [COUT][CIN][3][3] -> Wp [tap][cout][ci] bf16
//   [4448,5216) : QKV  qkv[mat][b][n][k] = cat(node,goal) @ W
// ---------------------------------------------------------------------------
__global__ __launch_bounds__(256) void prep_kernel(
    const float* __restrict__ state, const float* __restrict__ node_embeds,
    const float* __restrict__ goal_embed, const float* __restrict__ conv_w,
    const float* __restrict__ wQ, const float* __restrict__ wK,
    const float* __restrict__ wV,
    short* __restrict__ nhwc, short* __restrict__ Wp, float* __restrict__ qkv) {
  __shared__ __align__(16) unsigned char smem[33280];
  int bid = blockIdx.x, tid = threadIdx.x;

  if (bid < 4096) {
    // ---------- transpose one (b,y) row ----------
    int b = bid >> 7, y = bid & 127;
    unsigned* lds = (unsigned*)smem;              // [128 cells][32 dwords]
    int cp = tid >> 3;                            // ci pair: ci = 2cp, 2cp+1
    int xo = (tid & 7) << 4;                      // x offset, 16 x per thread
    const float* r0 = state + (((b * 64 + 2 * cp) * 128 + y) * 128) + xo;
    const float* r1 = r0 + 16384;                 // next ci row (+64KB)
    float4 a0[4], a1[4];
#pragma unroll
    for (int j = 0; j < 4; ++j) { a0[j] = *(const float4*)(r0 + 4 * j); a1[j] = *(const float4*)(r1 + 4 * j); }
    int k16 = cp >> 2;
    const float* f0 = (const float*)a0;
    const float* f1 = (const float*)a1;
#pragma unroll
    for (int jj = 0; jj < 16; ++jj) {
      int x = xo + jj;
      unsigned pk = (unsigned)f2bf(f0[jj]) | ((unsigned)f2bf(f1[jj]) << 16);
      lds[x * 32 + (((k16 + x + 1) & 7) << 2) + (cp & 3)] = pk;
    }
    __syncthreads();
    // coalesced store: thread t -> cell = t>>1, half = t&1 (64B each)
    int cell = tid >> 1, h = tid & 1;
    unsigned* rowbase = (unsigned*)nhwc + (size_t)((b * 130 + y + 1) * 136) * 32;
    unsigned* dst = rowbase + (cell + 1) * 32 + h * 16;
    unsigned* src = lds + cell * 32 + h * 16;
#pragma unroll
    for (int k = 0; k < 4; ++k) *(uint4*)(dst + 4 * k) = *(uint4*)(src + 4 * k);
    // zero x-pads of this row: cell 0 (32 dw) + cells 129..135 (224 dw)
    if (tid < 32) rowbase[tid] = 0;
    else rowbase[129 * 32 + (tid - 32)] = 0;
  } else if (bid < 4160) {
    // ---------- zero y-pad rows ----------
    int idx = bid - 4096;
    int b = idx >> 1, yp = (idx & 1) ? 129 : 0;
    unsigned* rowbase = (unsigned*)nhwc + (size_t)((b * 130 + yp) * 136) * 32;
    for (int k = tid; k < 136 * 32; k += 256) rowbase[k] = 0;
  } else if (bid < 4448) {
    // ---------- pack weights ----------
    int idx = (bid - 4160) * 256 + tid;
    if (idx < COUT_ * CIN_ * 9) {
      int cout = idx / (CIN_ * 9);
      int rem  = idx % (CIN_ * 9);
      int ci   = rem / 9;
      int tap  = rem % 9;
      Wp[(tap * COUT_ + cout) * CIN_ + ci] = (short)f2bf(conv_w[idx]);
    }
  } else {
    // ---------- QKV ----------
    int idx = bid - 4448;
    int kg = idx & 7;
    int r  = idx >> 3;
    int b  = r / 3;
    int mat = r - b * 3;
    const float* W = (mat == 0) ? wQ : (mat == 1) ? wK : wV;
    float (*x)[260] = (float(*)[260])smem;
    for (int e = tid; e < 4096; e += 256) x[e >> 7][e & 127] = node_embeds[e];
    for (int e = tid; e < 4096; e += 256) x[e >> 7][128 + (e & 127)] = goal_embed[b * 128 + (e & 127)];
    __syncthreads();
    int k  = kg * 16 + (tid & 15);
    int n0 = tid >> 4, n1 = n0 + 16;
    float a0 = 0.f, a1 = 0.f;
    for (int f = 0; f < 256; f += 4) {
      float4 xv0 = *(const float4*)&x[n0][f];
      float4 xv1 = *(const float4*)&x[n1][f];
      float w0 = W[(f + 0) * 128 + k];
      float w1 = W[(f + 1) * 128 + k];
      float w2 = W[(f + 2) * 128 + k];
      float w3 = W[(f + 3) * 128 + k];
      a0 += xv0.x * w0 + xv0.y * w1 + xv0.z * w2 + xv0.w * w3;
      a1 += xv1.x * w0 + xv1.y * w1 + xv1.z * w2 + xv1.w * w3;
    }
    int base = (mat * 32 + b) * 32;
    qkv[(base + n0) * 128 + k] = a0;
    qkv[(base + n1) * 128 + k] = a1;
  }
}

// ---------------------------------------------------------------------------
// scores + softmax + P@V -> atten[b][q][k].  grid 32 (b), block 256
// ---------------------------------------------------------------------------
__global__ void attn_kernel(const float* __restrict__ qkv, float* __restrict__ atten) {
  __shared__ float QS[32][132], KS[32][132], VS[32][132];
  __shared__ float S[32][33];
  int tid = threadIdx.x, b = blockIdx.x;
  const float* q0 = qkv + b * 4096;
  const float* k0 = qkv + 131072 + b * 4096;
  const float* v0 = qkv + 262144 + b * 4096;
  for (int e = tid; e < 4096; e += 256) {
    int n = e >> 7, k = e & 127;
    QS[n][k] = q0[e]; KS[n][k] = k0[e]; VS[n][k] = v0[e];
  }
  __syncthreads();
  for (int p = tid; p < 1024; p += 256) {
    int qi = p >> 5, ni = p & 31;
    float acc = 0.f;
    for (int k = 0; k < 128; k += 4) {
      float4 a = *(const float4*)&QS[qi][k];
      float4 c = *(const float4*)&KS[ni][k];
      acc += a.x * c.x + a.y * c.y + a.z * c.z + a.w * c.w;
    }
    S[qi][ni] = acc * 0.08838834764831845f;  // 1/sqrt(128)
  }
  __syncthreads();
  if (tid < 32) {
    float mx = -1e30f;
    for (int n = 0; n < 32; ++n) mx = fmaxf(mx, S[tid][n]);
    float sum = 0.f;
    for (int n = 0; n < 32; ++n) { float e = __expf(S[tid][n] - mx); S[tid][n] = e; sum += e; }
    float inv = 1.f / sum;
    for (int n = 0; n < 32; ++n) S[tid][n] *= inv;
  }
  __syncthreads();
  int qi = tid >> 3, ks = (tid & 7) * 16;
  float4 A0 = {0,0,0,0}, A1 = {0,0,0,0}, A2 = {0,0,0,0}, A3 = {0,0,0,0};
  for (int n = 0; n < 32; ++n) {
    float p = S[qi][n];
    float4 v_0 = *(const float4*)&VS[n][ks];
    float4 v_1 = *(const float4*)&VS[n][ks + 4];
    float4 v_2 = *(const float4*)&VS[n][ks + 8];
    float4 v_3 = *(const float4*)&VS[n][ks + 12];
    A0.x += p * v_0.x; A0.y += p * v_0.y; A0.z += p * v_0.z; A0.w += p * v_0.w;
    A1.x += p * v_1.x; A1.y += p * v_1.y; A1.z += p * v_1.z; A1.w += p * v_1.w;
    A2.x += p * v_2.x; A2.y += p * v_2.y; A2.z += p * v_2.z; A2.w += p * v_2.w;
    A3.x += p * v_3.x; A3.y += p * v_3.y; A3.z += p * v_3.z; A3.w += p * v_3.w;
  }
  float* op = atten + (b * 32 + qi) * 128 + ks;
  *(float4*)&op[0] = A0; *(float4*)&op[4] = A1; *(float4*)&op[8] = A2; *(float4*)&op[12] = A3;
}

// ---------------------------------------------------------------------------
// out_node[b][n][o] = fb[o] + sum_k atten[b][n][k] * fw[o][k]
// grid (32 n, 32 b), block 128
// ---------------------------------------------------------------------------
__global__ void final_kernel(const float* __restrict__ atten, const float* __restrict__ fw,
                             const float* __restrict__ fb, float* __restrict__ out_node) {
  __shared__ float ar[128];
  int tid = threadIdx.x;
  int n = blockIdx.x, b = blockIdx.y;
  ar[tid] = atten[(b * 32 + n) * 128 + tid];
  __syncthreads();
  const float* fr = fw + tid * 128;
  float acc = fb[tid];
  for (int k = 0; k < 128; k += 4) {
    float4 f = *(const float4*)&fr[k];
    acc += ar[k] * f.x + ar[k + 1] * f.y + ar[k + 2] * f.z + ar[k + 3] * f.w;
  }
  out_node[(b * 32 + n) * 128 + tid] = acc;
}

// ---------------------------------------------------------------------------
// Fused conv3x3 (bf16 implicit GEMM, MFMA 16x16x32) + gather-add epilogue
// Input: padded NHWC bf16, swizzled 16B chunks. Staging = pure global_load_lds.
// grid (64 ytiles, 2 xtiles, 32 b), block 256 (4 waves)
// C tile = 128 cout x 128 spatial (2 rows x 64 cols); K = 9 taps x 64 ci
// ---------------------------------------------------------------------------
#define XC 72   // LDS cells per row (66 needed, 72 loaded = 9 x 1KB chunks)
__global__ __launch_bounds__(256) void conv_kernel(
    const short* __restrict__ nhwc, const float* __restrict__ conv_b,
    const int* __restrict__ game_board, const int* __restrict__ char_to_node,
    const short* __restrict__ Wp, const float* __restrict__ out_node,
    float* __restrict__ out) {
  __shared__ __align__(16) short tile[4 * XC * 64];   // 36864 B, [row][cell][ci(swizzled)]
  int tid = threadIdx.x;
  int lane = tid & 63, wave = tid >> 6;
  int y0 = blockIdx.x * 2;
  int x0 = blockIdx.y * 64;
  int b  = blockIdx.z;

  // ---- stage: wave w loads LDS row w (padded y = y0+w), 9 chunks x 1KB ----
  {
    const short* grow = nhwc + (size_t)((b * 130 + y0 + wave) * 136 + x0) * 64;
    short* lrow = tile + wave * (XC * 64);
#pragma unroll
    for (int ch = 0; ch < 9; ++ch)
      gl2lds16(grow + ch * 512 + lane * 8, lrow + ch * 512 + lane * 8);
  }
  __syncthreads();

  int q = lane >> 4, i = lane & 15;
  int mtset = (wave >> 1) * 4;   // m-tile base: waves {0,1}->couts 0..63, {2,3}->64..127
  int ty    = wave & 1;          // output row within tile

  f32x4 acc[4][4];
#pragma unroll
  for (int m = 0; m < 4; ++m)
#pragma unroll
    for (int n = 0; n < 4; ++n) acc[m][n] = (f32x4){0.f, 0.f, 0.f, 0.f};

  // A-frag: Wp[t][cout][h*32 + q*8 + j], cout = (mtset+m)*16 + i
  const short* wbase = Wp + i * 64 + q * 8;
  bf16x8 aF[4];
#pragma unroll
  for (int m = 0; m < 4; ++m) aF[m] = *(const bf16x8*)(wbase + (mtset + m) * 1024);

  for (int chunk = 0; chunk < 18; ++chunk) {
    int t = chunk >> 1, h = chunk & 1;
    int kh = t / 3, kw = t - kh * 3;
    int row = ty + kh;
    bf16x8 bF[4];
#pragma unroll
    for (int ntl = 0; ntl < 4; ++ntl) {
      int c = ntl * 16 + i + kw;
      bF[ntl] = *(const bf16x8*)(tile + (row * XC + c) * 64 + (((h * 4 + q + c) & 7) << 3));
    }
    bf16x8 aN[4];
    if (chunk < 17) {                       // prefetch next chunk's A-frags (L2-hit)
      int c2 = chunk + 1;
      const short* wb2 = wbase + (c2 >> 1) * 8192 + (c2 & 1) * 32;
#pragma unroll
      for (int m = 0; m < 4; ++m) aN[m] = *(const bf16x8*)(wb2 + (mtset + m) * 1024);
    }
#pragma unroll
    for (int m = 0; m < 4; ++m)
#pragma unroll
      for (int n = 0; n < 4; ++n)
        acc[m][n] = __builtin_amdgcn_mfma_f32_16x16x32_bf16(aF[m], bF[n], acc[m][n], 0, 0, 0);
    if (chunk < 17) {
#pragma unroll
      for (int m = 0; m < 4; ++m) aF[m] = aN[m];
    }
  }

  // ---- epilogue: bias + gather(out_node) + store ----
  int gy = y0 + ty;
#pragma unroll
  for (int ntl = 0; ntl < 4; ++ntl) {
    int gx = x0 + ntl * 16 + i;
    int gb = game_board[(b * 128 + gy) * 128 + gx];
    bool valid = (gb >= 0 && gb < 32);
    int nidx = 0;
    if (valid) { nidx = char_to_node[gb]; nidx = nidx < 0 ? 0 : (nidx > 31 ? 31 : nidx); }
    const float* gn = out_node + (b * 32 + nidx) * 128;
#pragma unroll
    for (int m = 0; m < 4; ++m) {
      int c0 = (mtset + m) * 16 + q * 4;          // cout of reg 0
      float4 bias = *(const float4*)(conv_b + c0);
      float4 g = valid ? *(const float4*)(gn + c0) : make_float4(0.f, 0.f, 0.f, 0.f);
      f32x4 a = acc[m][ntl];
      int obase = (b * 128 + c0) * 16384 + gy * 128 + gx;
      out[obase]         = a[0] + bias.x + g.x;
      out[obase + 16384] = a[1] + bias.y + g.y;
      out[obase + 32768] = a[2] + bias.z + g.z;
      out[obase + 49152] = a[3] + bias.w + g.w;
    }
  }
}

// ---------------------------------------------------------------------------
extern "C" void kernel_launch(void* const* d_in, const int* in_sizes, int n_in,
                              void* d_out, int out_size, void* d_ws, size_t ws_size,
                              hipStream_t stream) {
  const int*   game_board   = (const int*)  d_in[0];
  const float* state        = (const float*)d_in[1];
  const float* node_embeds  = (const float*)d_in[2];
  const float* goal_embed   = (const float*)d_in[3];
  const int*   char_to_node = (const int*)  d_in[4];
  const float* conv_w       = (const float*)d_in[5];
  const float* conv_b       = (const float*)d_in[6];
  const float* wQ           = (const float*)d_in[7];
  const float* wK           = (const float*)d_in[8];
  const float* wV           = (const float*)d_in[9];
  const float* final_w      = (const float*)d_in[10];
  const float* final_b      = (const float*)d_in[11];
  float* out = (float*)d_out;

  char* ws = (char*)d_ws;
  short* Wp       = (short*)(ws);             // 147456 B   bf16 weights [9][128][64]
  float* qkv      = (float*)(ws + 147456);    // 1572864 B  [3][32][32][128] fp32
  float* atten    = (float*)(ws + 1720320);   // 524288 B   [32][32][128] fp32
  float* out_node = (float*)(ws + 2244608);   // 524288 B   [32][32][128] fp32
  short* nhwc     = (short*)(ws + 2768896);   // 72417280 B [32][130][136][64] bf16 padded+swizzled

  hipLaunchKernelGGL(prep_kernel, dim3(5216), dim3(256), 0, stream,
                     state, node_embeds, goal_embed, conv_w, wQ, wK, wV, nhwc, Wp, qkv);
  hipLaunchKernelGGL(attn_kernel, dim3(32), dim3(256), 0, stream, qkv, atten);
  hipLaunchKernelGGL(final_kernel, dim3(32, 32), dim3(128), 0, stream, atten, final_w, final_b, out_node);
  hipLaunchKernelGGL(conv_kernel, dim3(64, 2, 32), dim3(256), 0, stream,
                     nhwc, conv_b, game_board, char_to_node, Wp, out_node, out);
}